// Round 2
// baseline (961.296 us; speedup 1.0000x reference)
//
#include <hip/hip_runtime.h>
#include <hip/hip_bf16.h>

typedef unsigned int u32;

// ---------------------------------------------------------------------------
// edge_index may be int64 (jax x64 enabled) or int32 (default jax demotion).
// Detect on device: for int64, the high 32-bit word of every element is 0.
// ---------------------------------------------------------------------------
__global__ void detect_i64_kernel(const u32* __restrict__ ei, u32* __restrict__ flag, int nchk)
{
    __shared__ u32 s_any;
    if (threadIdx.x == 0) s_any = 0u;
    __syncthreads();
    for (int i = threadIdx.x; i < nchk; i += blockDim.x)
        if (ei[2 * i + 1] != 0u) atomicOr(&s_any, 1u);
    __syncthreads();
    if (threadIdx.x == 0) *flag = (s_any ? 0u : 1u);   // 1 == int64 layout
}

__device__ __forceinline__ void load_edge(const void* ei, long long E, int e, int is64,
                                          u32& src, u32& dst)
{
    if (is64) {
        const unsigned long long* p = (const unsigned long long*)ei;
        src = (u32)p[e];
        dst = (u32)p[E + e];
    } else {
        const u32* p = (const u32*)ei;
        src = p[e];
        dst = p[E + e];
    }
}

// ---------------------------------------------------------------------------
// CSR build: degree histogram -> exclusive scan -> slot fill
// ---------------------------------------------------------------------------
__global__ __launch_bounds__(256) void count_kernel(const void* __restrict__ ei, long long E,
                                                    const u32* __restrict__ flag,
                                                    u32* __restrict__ deg)
{
    int e = blockIdx.x * 256 + threadIdx.x;
    if (e >= (int)E) return;
    int is64 = (int)flag[0];
    u32 src, dst;
    load_edge(ei, E, e, is64, src, dst);
    atomicAdd(&deg[dst], 1u);
}

__global__ __launch_bounds__(256) void scan_block_kernel(const u32* __restrict__ deg,
                                                         u32* __restrict__ rowptr,
                                                         u32* __restrict__ partial, int n)
{
    __shared__ u32 s[256];
    int t = threadIdx.x;
    int i = blockIdx.x * 256 + t;
    u32 v = (i < n) ? deg[i] : 0u;
    s[t] = v;
    __syncthreads();
    for (int off = 1; off < 256; off <<= 1) {
        u32 tmp = (t >= off) ? s[t - off] : 0u;
        __syncthreads();
        s[t] += tmp;
        __syncthreads();
    }
    if (i < n) rowptr[i] = s[t] - v;           // exclusive within block
    if (t == 255) partial[blockIdx.x] = s[255]; // block total
}

__global__ __launch_bounds__(512) void scan_partials_kernel(const u32* __restrict__ partial,
                                                            u32* __restrict__ pscan, int nb)
{
    __shared__ u32 s[512];
    int t = threadIdx.x;
    u32 v = (t < nb) ? partial[t] : 0u;
    s[t] = v;
    __syncthreads();
    for (int off = 1; off < 512; off <<= 1) {
        u32 tmp = (t >= off) ? s[t - off] : 0u;
        __syncthreads();
        s[t] += tmp;
        __syncthreads();
    }
    if (t < nb) pscan[t] = s[t] - v;           // exclusive across blocks
}

__global__ __launch_bounds__(256) void add_offsets_kernel(u32* __restrict__ rowptr,
                                                          const u32* __restrict__ pscan,
                                                          int n, u32 total)
{
    int i = blockIdx.x * 256 + threadIdx.x;
    if (i < n) rowptr[i] += pscan[blockIdx.x];
    if (i == 0) rowptr[n] = total;
}

__global__ __launch_bounds__(256) void fill_kernel(const void* __restrict__ ei, long long E,
                                                   const u32* __restrict__ flag,
                                                   const u32* __restrict__ rowptr,
                                                   u32* __restrict__ fillcnt,
                                                   u32* __restrict__ col)
{
    int e = blockIdx.x * 256 + threadIdx.x;
    if (e >= (int)E) return;
    int is64 = (int)flag[0];
    u32 src, dst;
    load_edge(ei, E, e, is64, src, dst);
    u32 pos = rowptr[dst] + atomicAdd(&fillcnt[dst], 1u);
    col[pos] = src;
}

// ---------------------------------------------------------------------------
// Mean aggregation: one wave per dst node. Lane l owns columns 2l, 2l+1.
// Coalesced 512B row gathers; no atomics; writes mean (pre-divided).
// 4-deep unrolled gather: 4 independent row loads in flight per lane to
// cover ~200cy L2-hit latency (avg degree 16 -> 4 iations of the unrolled body).
// ---------------------------------------------------------------------------
__global__ __launch_bounds__(256) void agg_kernel(const float* __restrict__ H,
                                                  const u32* __restrict__ col,
                                                  const u32* __restrict__ rowptr,
                                                  float* __restrict__ out, int n)
{
    int wave = threadIdx.x >> 6;
    int lane = threadIdx.x & 63;
    int node = blockIdx.x * 4 + wave;
    if (node >= n) return;
    u32 b0 = rowptr[node], b1 = rowptr[node + 1];
    float ax = 0.f, ay = 0.f;
    u32 j = b0;
    for (; j + 4 <= b1; j += 4) {            // 4 independent gathers in flight
        u32 s0 = col[j], s1 = col[j + 1], s2 = col[j + 2], s3 = col[j + 3];
        float2 v0 = *(const float2*)(H + (size_t)s0 * 128 + lane * 2);
        float2 v1 = *(const float2*)(H + (size_t)s1 * 128 + lane * 2);
        float2 v2 = *(const float2*)(H + (size_t)s2 * 128 + lane * 2);
        float2 v3 = *(const float2*)(H + (size_t)s3 * 128 + lane * 2);
        ax += v0.x; ay += v0.y;
        ax += v1.x; ay += v1.y;
        ax += v2.x; ay += v2.y;
        ax += v3.x; ay += v3.y;
    }
    for (; j < b1; ++j) {
        u32 s0 = col[j];
        float2 v0 = *(const float2*)(H + (size_t)s0 * 128 + lane * 2);
        ax += v0.x; ay += v0.y;
    }
    float inv = (b1 > b0) ? 1.0f / (float)(b1 - b0) : 1.0f;  // max(cnt,1)
    *(float2*)(out + (size_t)node * 128 + lane * 2) = make_float2(ax * inv, ay * inv);
}

// ---------------------------------------------------------------------------
// Fused: out = prelu(mean @ Wl^T + X @ Wr^T + bl, alpha)
// 64 rows x 128 cols per block, K-chunks of 32 staged in LDS.
// A-tiles row-major (+1 pad -> broadcast reads); W-tiles k-major stride 132
// (528B = 33*16B keeps float4 reads 16B-aligned). 8x4 acc per thread.
// Safe to run IN-PLACE (out == X): each block reads only rows it writes
// (the boundary clamp grow=min(grow,n-1) stays inside the last block's own
// range), and all reads complete before the epilogue stores.
// ---------------------------------------------------------------------------
__global__ __launch_bounds__(256) void gemm_prelu_kernel(
    const float* __restrict__ M, const float* __restrict__ X,
    const float* __restrict__ Wl, const float* __restrict__ bl,
    const float* __restrict__ Wr, const float* __restrict__ al,
    float* __restrict__ out, int n)
{
    __shared__ float sM[64][33];
    __shared__ float sX[64][33];
    __shared__ float sWl[32][132];
    __shared__ float sWr[32][132];

    const int t = threadIdx.x;
    const int row0 = blockIdx.x * 64;
    const int c0 = (t & 31) * 4;
    const int r0 = (t >> 5) * 8;

    float acc[8][4];
#pragma unroll
    for (int r = 0; r < 8; ++r)
#pragma unroll
        for (int c = 0; c < 4; ++c) acc[r][c] = 0.f;

    const float4 bl4 = *(const float4*)(bl + c0);
    const float4 al4 = *(const float4*)(al + c0);

    const int lr = t >> 3;        // 0..31 : A-tile row
    const int lk = (t & 7) * 4;   // 0..28 : A-tile k
    const int wc = t >> 1;        // 0..127: W col
    const int wk0 = (t & 1) * 4;  // 0 | 4 : W k start

    for (int kc = 0; kc < 128; kc += 32) {
        __syncthreads();
#pragma unroll
        for (int half = 0; half < 2; ++half) {
            int rr = lr + half * 32;
            int grow = row0 + rr;
            if (grow > n - 1) grow = n - 1;
            const float4 a = *(const float4*)(M + (size_t)grow * 128 + kc + lk);
            const float4 b = *(const float4*)(X + (size_t)grow * 128 + kc + lk);
            sM[rr][lk + 0] = a.x; sM[rr][lk + 1] = a.y; sM[rr][lk + 2] = a.z; sM[rr][lk + 3] = a.w;
            sX[rr][lk + 0] = b.x; sX[rr][lk + 1] = b.y; sX[rr][lk + 2] = b.z; sX[rr][lk + 3] = b.w;
        }
        for (int kk = wk0; kk < 32; kk += 8) {
            const float4 wl = *(const float4*)(Wl + (size_t)wc * 128 + kc + kk);
            const float4 wr = *(const float4*)(Wr + (size_t)wc * 128 + kc + kk);
            sWl[kk + 0][wc] = wl.x; sWl[kk + 1][wc] = wl.y; sWl[kk + 2][wc] = wl.z; sWl[kk + 3][wc] = wl.w;
            sWr[kk + 0][wc] = wr.x; sWr[kk + 1][wc] = wr.y; sWr[kk + 2][wc] = wr.z; sWr[kk + 3][wc] = wr.w;
        }
        __syncthreads();

        for (int kk = 0; kk < 32; ++kk) {
            const float4 wl4 = *(const float4*)(&sWl[kk][c0]);
            const float4 wr4 = *(const float4*)(&sWr[kk][c0]);
#pragma unroll
            for (int r = 0; r < 8; ++r) {
                const float m = sM[r0 + r][kk];
                const float x = sX[r0 + r][kk];
                acc[r][0] += m * wl4.x; acc[r][0] += x * wr4.x;
                acc[r][1] += m * wl4.y; acc[r][1] += x * wr4.y;
                acc[r][2] += m * wl4.z; acc[r][2] += x * wr4.z;
                acc[r][3] += m * wl4.w; acc[r][3] += x * wr4.w;
            }
        }
    }

#pragma unroll
    for (int r = 0; r < 8; ++r) {
        const int grow = row0 + r0 + r;
        if (grow < n) {
            float4 o;
            float v;
            v = acc[r][0] + bl4.x; o.x = (v >= 0.f) ? v : al4.x * v;
            v = acc[r][1] + bl4.y; o.y = (v >= 0.f) ? v : al4.y * v;
            v = acc[r][2] + bl4.z; o.z = (v >= 0.f) ? v : al4.z * v;
            v = acc[r][3] + bl4.w; o.w = (v >= 0.f) ? v : al4.w * v;
            *(float4*)(out + (size_t)grow * 128 + c0) = o;
        }
    }
}

// ---------------------------------------------------------------------------
extern "C" void kernel_launch(void* const* d_in, const int* in_sizes, int n_in,
                              void* d_out, int out_size, void* d_ws, size_t ws_size,
                              hipStream_t stream)
{
    const float* x   = (const float*)d_in[0];
    const void*  ei  = d_in[1];
    const float* Wl1 = (const float*)d_in[2],  *bl1 = (const float*)d_in[3];
    const float* Wr1 = (const float*)d_in[4],  *a1  = (const float*)d_in[5];
    const float* Wl2 = (const float*)d_in[6],  *bl2 = (const float*)d_in[7];
    const float* Wr2 = (const float*)d_in[8],  *a2  = (const float*)d_in[9];
    const float* Wl3 = (const float*)d_in[10], *bl3 = (const float*)d_in[11];
    const float* Wr3 = (const float*)d_in[12], *a3  = (const float*)d_in[13];
    float* out = (float*)d_out;

    const int       N = in_sizes[0] / 128;
    const long long E = in_sizes[1] / 2;

    // bump allocator over d_ws (needs ~60 MB)
    char* p = (char*)d_ws;
    auto alloc = [&](size_t bytes) {
        char* r = p;
        p += (bytes + 255) & ~(size_t)255;
        return (void*)r;
    };
    u32* deg     = (u32*)alloc((size_t)N * 4);
    u32* rowptr  = (u32*)alloc(((size_t)N + 1) * 4);
    u32* fillcnt = (u32*)alloc((size_t)N * 4);
    u32* partial = (u32*)alloc(512 * 4);
    u32* pscan   = (u32*)alloc(512 * 4);
    u32* flag    = (u32*)alloc(256);
    u32* col     = (u32*)alloc((size_t)E * 4);
    float* aggb  = (float*)alloc((size_t)N * 128 * 4);

    hipMemsetAsync(deg, 0, (size_t)N * 4, stream);
    hipMemsetAsync(fillcnt, 0, (size_t)N * 4, stream);

    detect_i64_kernel<<<1, 256, 0, stream>>>((const u32*)ei, flag, 2048);

    const int eblocks = (int)((E + 255) / 256);
    const int nb      = (N + 255) / 256;

    count_kernel<<<eblocks, 256, 0, stream>>>(ei, E, flag, deg);
    scan_block_kernel<<<nb, 256, 0, stream>>>(deg, rowptr, partial, N);
    scan_partials_kernel<<<1, 512, 0, stream>>>(partial, pscan, nb);
    add_offsets_kernel<<<nb, 256, 0, stream>>>(rowptr, pscan, N, (u32)E);
    fill_kernel<<<eblocks, 256, 0, stream>>>(ei, E, flag, rowptr, fillcnt, col);

    const int ablocks = (N + 3) / 4;
    const int gblocks = (N + 63) / 64;

    // layer 1: x -> d_out
    agg_kernel<<<ablocks, 256, 0, stream>>>(x, col, rowptr, aggb, N);
    gemm_prelu_kernel<<<gblocks, 256, 0, stream>>>(aggb, x, Wl1, bl1, Wr1, a1, out, N);
    // layer 2: d_out -> d_out (in-place GEMM is safe: blocks touch only own rows)
    agg_kernel<<<ablocks, 256, 0, stream>>>(out, col, rowptr, aggb, N);
    gemm_prelu_kernel<<<gblocks, 256, 0, stream>>>(aggb, out, Wl2, bl2, Wr2, a2, out, N);
    // layer 3: d_out -> d_out
    agg_kernel<<<ablocks, 256, 0, stream>>>(out, col, rowptr, aggb, N);
    gemm_prelu_kernel<<<gblocks, 256, 0, stream>>>(aggb, out, Wl3, bl3, Wr3, a3, out, N);
}